// Round 2
// baseline (7357.406 us; speedup 1.0000x reference)
//
#include <hip/hip_runtime.h>
#include <stdint.h>

// ---------------------------------------------------------------------------
// 2-layer LSTM (B=64,T=128,NA=2048,H=1024) + softmax head, bf16x3 MFMA.
//   1) W decompose+transpose to bf16 (hi,lo) [N][K]
//   2) per 32-step chunk: X-chunk decompose; Z0x_chunk = Xc @ W0x (MFMA GEMM)
//   3) 129 pipelined step launches: launch t does L0(t) || L1(t-1)
//   4) logits @ Wout + softmax
// Precision: z = a_hi*b_hi + a_hi*b_lo + a_lo*b_hi (fp32 accum, fp32 c-state)
// ws footprint ~153 MiB, guarded against ws_size.
// ---------------------------------------------------------------------------

typedef __attribute__((ext_vector_type(4))) float f32x4;
typedef __attribute__((ext_vector_type(8))) short short8x;
typedef unsigned short ushort_t;

constexpr int B_  = 64;
constexpr int T_  = 128;
constexpr int NA_ = 2048;
constexpr int H_  = 1024;
constexpr int C_  = 10;
constexpr int BT_ = B_ * T_;     // 8192
constexpr int G4_ = 4 * H_;      // 4096
constexpr int HB_ = B_ * H_;     // 65536 (parity stride for h buffers)
constexpr int CH_ = 32;          // timesteps per GEMM chunk
constexpr int MC_ = B_ * CH_;    // 2048 rows per chunk

__device__ __forceinline__ ushort_t f2bf(float x) {
    uint32_t u = __float_as_uint(x);
    uint32_t r = (u + 0x7FFFu + ((u >> 16) & 1u)) >> 16;   // RNE
    return (ushort_t)r;
}
__device__ __forceinline__ float bf2f(ushort_t h) {
    return __uint_as_float((uint32_t)h << 16);
}
__device__ __forceinline__ float sigmf(float x) { return 1.0f / (1.0f + expf(-x)); }

#define GLOAD_LDS(gp, lp) \
    __builtin_amdgcn_global_load_lds((const __attribute__((address_space(1))) uint32_t*)(gp), \
                                     (__attribute__((address_space(3))) uint32_t*)(lp), 16, 0, 0)

// ---------------------------------------------------------------------------
// X chunk c -> (hi, lo) bf16 decompose with row remap m' = b*CH + (t & 31)
// ---------------------------------------------------------------------------
__global__ void decomp_chunk(const float* __restrict__ X, int c,
                             ushort_t* __restrict__ Hi, ushort_t* __restrict__ Lo) {
    const int i = blockIdx.x * blockDim.x + threadIdx.x;   // float4 index
    if (i >= MC_ * NA_ / 4) return;
    const int mp = i >> 9;          // / (NA_/4 = 512)
    const int kq = i & 511;
    const int b = mp >> 5, j = mp & 31;
    const size_t src = ((size_t)(b * T_ + c * CH_ + j)) * NA_ + (size_t)kq * 4;
    float4 v = *(const float4*)(X + src);
    ushort4 hi, lo;
    hi.x = f2bf(v.x); lo.x = f2bf(v.x - bf2f(hi.x));
    hi.y = f2bf(v.y); lo.y = f2bf(v.y - bf2f(hi.y));
    hi.z = f2bf(v.z); lo.z = f2bf(v.z - bf2f(hi.z));
    hi.w = f2bf(v.w); lo.w = f2bf(v.w - bf2f(hi.w));
    ((ushort4*)Hi)[i] = hi;
    ((ushort4*)Lo)[i] = lo;
}

// ---------------------------------------------------------------------------
// W[rowOff .. rowOff+Klen-1][0..4095] fp32 -> T{hi,lo}[n][k] bf16  (transpose)
// ---------------------------------------------------------------------------
__global__ void transdec(const float* __restrict__ W, int rowOff, int Klen,
                         ushort_t* __restrict__ Thi, ushort_t* __restrict__ Tlo) {
    __shared__ float tile[32][33];
    const int k0 = blockIdx.x * 32, n0 = blockIdx.y * 32;
    const int tx = threadIdx.x & 31, ty = threadIdx.x >> 5;   // 256 thr: ty 0..7
#pragma unroll
    for (int i = 0; i < 32; i += 8)
        tile[ty + i][tx] = W[(size_t)(rowOff + k0 + ty + i) * G4_ + n0 + tx];
    __syncthreads();
#pragma unroll
    for (int i = 0; i < 32; i += 8) {
        float v = tile[tx][ty + i];
        int n = n0 + ty + i;
        size_t o = (size_t)n * Klen + k0 + tx;
        ushort_t hi = f2bf(v);
        Thi[o] = hi;
        Tlo[o] = f2bf(v - bf2f(hi));
    }
}

// ---------------------------------------------------------------------------
// C[M][N] (fp32) = A[M][K] x Bt[N][K]^T  with bf16x3; m97-style structure:
// 128x128 tile, BK=64, global_load_lds w16, XOR-swizzled LDS, 2 barriers/K-step
// ---------------------------------------------------------------------------
__global__ __launch_bounds__(256, 2)
void gemm_bf16x3(const ushort_t* __restrict__ Ahi, const ushort_t* __restrict__ Alo,
                 const ushort_t* __restrict__ Bhi, const ushort_t* __restrict__ Blo,
                 float* __restrict__ C, int M, int N, int K) {
    __shared__ ushort_t sA[2][128 * 64];   // [hi/lo] 16KB each
    __shared__ ushort_t sB[2][128 * 64];

    const int tid  = threadIdx.x;
    const int lane = tid & 63;
    const int wv   = tid >> 6;
    const int wr   = wv >> 1, wc = wv & 1;         // 2x2 waves of 64x64
    const int tm   = blockIdx.y * 128, tn = blockIdx.x * 128;

    f32x4 acc[4][4] = {};

    for (int k0 = 0; k0 < K; k0 += 64) {
        // stage; physical LDS linear, source pre-swizzled (rule #21)
#pragma unroll
        for (int rd = 0; rd < 4; ++rd) {
            const int off = rd * 4096 + tid * 16;            // physical byte
            const int r   = off >> 7;                        // 128B rows
            const int kc  = ((off >> 4) & 7) ^ (r & 7);      // logical k-chunk
            const size_t aoff = (size_t)(tm + r) * K + k0 + kc * 8;
            const size_t boff = (size_t)(tn + r) * K + k0 + kc * 8;
            const int dst = (rd * 4096 + wv * 1024) >> 1;    // ushort elements
            GLOAD_LDS(Ahi + aoff, (ushort_t*)sA[0] + dst);
            GLOAD_LDS(Alo + aoff, (ushort_t*)sA[1] + dst);
            GLOAD_LDS(Bhi + boff, (ushort_t*)sB[0] + dst);
            GLOAD_LDS(Blo + boff, (ushort_t*)sB[1] + dst);
        }
        __syncthreads();
#pragma unroll
        for (int ks = 0; ks < 2; ++ks) {
            short8x ah[4], al[4], bh[4], bl[4];
#pragma unroll
            for (int i = 0; i < 4; ++i) {
                const int kc = ks * 4 + (lane >> 4);
                const int ra = wr * 64 + i * 16 + (lane & 15);
                const int ea = ra * 64 + ((kc ^ (ra & 7)) * 8);
                ah[i] = *(const short8x*)(&sA[0][ea]);
                al[i] = *(const short8x*)(&sA[1][ea]);
                const int rb = wc * 64 + i * 16 + (lane & 15);
                const int eb = rb * 64 + ((kc ^ (rb & 7)) * 8);
                bh[i] = *(const short8x*)(&sB[0][eb]);
                bl[i] = *(const short8x*)(&sB[1][eb]);
            }
#pragma unroll
            for (int i = 0; i < 4; ++i)
#pragma unroll
                for (int j = 0; j < 4; ++j) {
                    acc[i][j] = __builtin_amdgcn_mfma_f32_16x16x32_bf16(ah[i], bh[j], acc[i][j], 0, 0, 0);
                    acc[i][j] = __builtin_amdgcn_mfma_f32_16x16x32_bf16(ah[i], bl[j], acc[i][j], 0, 0, 0);
                    acc[i][j] = __builtin_amdgcn_mfma_f32_16x16x32_bf16(al[i], bh[j], acc[i][j], 0, 0, 0);
                }
        }
        __syncthreads();
    }
    // epilogue: C/D layout col=lane&15, row=(lane>>4)*4+q  (m89-verified)
#pragma unroll
    for (int i = 0; i < 4; ++i)
#pragma unroll
        for (int j = 0; j < 4; ++j)
#pragma unroll
            for (int q = 0; q < 4; ++q) {
                const int row = tm + wr * 64 + i * 16 + (lane >> 4) * 4 + q;
                const int col = tn + wc * 64 + j * 16 + (lane & 15);
                C[(size_t)row * N + col] = acc[i][j][q];
            }
}

// ---------------------------------------------------------------------------
// Pipelined LSTM step: launch t does L0(step t) on WGs 0..63 and
// L1(step t-1) on WGs 64..127. 512 thr = 8 waves: gate g=wv&3, m-half=wv>>2.
// A (=h) staged in LDS; W read direct from global (B-fragment, L2/L3-resident).
// ---------------------------------------------------------------------------
__global__ __launch_bounds__(512, 2)
void lstm_step(int t,
               const float* __restrict__ Z0c,
               const ushort_t* __restrict__ W0hT_hi, const ushort_t* __restrict__ W0hT_lo,
               const ushort_t* __restrict__ W1T_hi,  const ushort_t* __restrict__ W1T_lo,
               const float* __restrict__ b0, const float* __restrict__ b1,
               ushort_t* __restrict__ h0hi, ushort_t* __restrict__ h0lo,
               ushort_t* __restrict__ h1hi, ushort_t* __restrict__ h1lo,
               float* __restrict__ c0, float* __restrict__ c1,
               ushort_t* __restrict__ hs) {
    const int wg = blockIdx.x;
    const bool L0 = (wg < 64);
    if (L0) { if (t >= T_) return; } else { if (t < 1) return; }
    const int tt = L0 ? t : (t - 1);
    const int u0 = (L0 ? wg : wg - 64) * 16;

    const int tid = threadIdx.x, lane = tid & 63, wv = tid >> 6;
    const int g = wv & 3, mh = wv >> 2;

    const ushort_t *A0hi, *A0lo, *A1hi = nullptr, *A1lo = nullptr;
    const ushort_t *Whi, *Wlo;
    int K;
    if (L0) {
        K = H_;
        Whi = W0hT_hi; Wlo = W0hT_lo;
        A0hi = h0hi + ((tt + 1) & 1) * HB_;   // h0(t-1)
        A0lo = h0lo + ((tt + 1) & 1) * HB_;
    } else {
        K = 2 * H_;
        Whi = W1T_hi; Wlo = W1T_lo;
        A0hi = h0hi + (tt & 1) * HB_;          // h0(t)   (k < 1024)
        A0lo = h0lo + (tt & 1) * HB_;
        A1hi = h1hi + ((tt + 1) & 1) * HB_;    // h1(t-1) (k >= 1024)
        A1lo = h1lo + ((tt + 1) & 1) * HB_;
    }

    __shared__ ushort_t sAh[64 * 64], sAl[64 * 64];   // 8KB each
    __shared__ float zl[4][64][16];                    // 16KB gate exchange

    // staging coords (physical-linear dest, pre-swizzled source)
    const int s_off = tid * 16;                 // byte in 8KB tile
    const int s_r   = s_off >> 7;               // row 0..63 (128B rows)
    const int s_kc  = ((s_off >> 4) & 7) ^ (s_r & 7);
    ushort_t* sAh_dst = sAh + ((wv * 1024) >> 1);
    ushort_t* sAl_dst = sAl + ((wv * 1024) >> 1);

    const int nrow = g * H_ + u0 + (lane & 15);
    const ushort_t* bph = Whi + (size_t)nrow * K + (lane >> 4) * 8;
    const ushort_t* bpl = Wlo + (size_t)nrow * K + (lane >> 4) * 8;

    f32x4 acc[2] = {};
    const int niter = K / 64;
    for (int it = 0; it < niter; ++it) {
        const int kk = it * 64;
        const ushort_t *abh, *abl;
        int ak;
        if (L0 || kk < H_) { abh = A0hi; abl = A0lo; ak = kk; }
        else               { abh = A1hi; abl = A1lo; ak = kk - H_; }
        GLOAD_LDS(abh + (size_t)s_r * H_ + ak + s_kc * 8, sAh_dst);
        GLOAD_LDS(abl + (size_t)s_r * H_ + ak + s_kc * 8, sAl_dst);
        __syncthreads();
#pragma unroll
        for (int ks = 0; ks < 2; ++ks) {
            short8x bh = *(const short8x*)(bph + kk + ks * 32);
            short8x bl = *(const short8x*)(bpl + kk + ks * 32);
#pragma unroll
            for (int i = 0; i < 2; ++i) {
                const int r  = mh * 32 + i * 16 + (lane & 15);
                const int kc = ks * 4 + (lane >> 4);
                const int e  = r * 64 + ((kc ^ (r & 7)) * 8);
                short8x ah = *(const short8x*)(&sAh[e]);
                short8x al = *(const short8x*)(&sAl[e]);
                acc[i] = __builtin_amdgcn_mfma_f32_16x16x32_bf16(ah, bh, acc[i], 0, 0, 0);
                acc[i] = __builtin_amdgcn_mfma_f32_16x16x32_bf16(ah, bl, acc[i], 0, 0, 0);
                acc[i] = __builtin_amdgcn_mfma_f32_16x16x32_bf16(al, bh, acc[i], 0, 0, 0);
            }
        }
        __syncthreads();
    }

    // gate exchange
#pragma unroll
    for (int i = 0; i < 2; ++i)
#pragma unroll
        for (int q = 0; q < 4; ++q)
            zl[g][mh * 32 + i * 16 + (lane >> 4) * 4 + q][lane & 15] = acc[i][q];
    __syncthreads();

    const float* bias = L0 ? b0 : b1;
    const int u  = tid & 15;
    const int uu = u0 + u;
#pragma unroll
    for (int mm = 0; mm < 2; ++mm) {
        const int m = (tid >> 4) * 2 + mm;
        float zi = zl[0][m][u] + bias[uu];
        float zj = zl[1][m][u] + bias[H_ + uu];
        float zf = zl[2][m][u] + bias[2 * H_ + uu];
        float zo = zl[3][m][u] + bias[3 * H_ + uu];
        float* cp;
        ushort_t *dh, *dl;
        if (L0) {
            // Z0x chunk row: m' = m*CH + (tt & 31); chunk = tt>>5 is the live buffer
            const float* zr = Z0c + (size_t)(m * CH_ + (tt & (CH_ - 1))) * G4_;
            zi += zr[uu]; zj += zr[H_ + uu]; zf += zr[2 * H_ + uu]; zo += zr[3 * H_ + uu];
            cp = c0 + m * H_ + uu;
            dh = h0hi + (tt & 1) * HB_ + m * H_ + uu;
            dl = h0lo + (tt & 1) * HB_ + m * H_ + uu;
        } else {
            cp = c1 + m * H_ + uu;
            dh = h1hi + (tt & 1) * HB_ + m * H_ + uu;
            dl = h1lo + (tt & 1) * HB_ + m * H_ + uu;
        }
        const float cold = *cp;
        const float cn = cold * sigmf(zf + 1.0f) + sigmf(zi) * tanhf(zj);
        const float h  = tanhf(cn) * sigmf(zo);
        *cp = cn;
        const ushort_t hh = f2bf(h);
        *dh = hh;
        *dl = f2bf(h - bf2f(hh));
        if (!L0) hs[(size_t)(m * T_ + tt) * H_ + uu] = f2bf(h);
    }
}

// ---------------------------------------------------------------------------
// logits = hs @ Wout + bout; softmax over C=10.  One wave per (b,t) row.
// ---------------------------------------------------------------------------
__global__ __launch_bounds__(256)
void out_softmax(const ushort_t* __restrict__ hs, const float* __restrict__ Wout,
                 const float* __restrict__ bout, float* __restrict__ out) {
    const int row  = blockIdx.x * 4 + (threadIdx.x >> 6);
    const int lane = threadIdx.x & 63;
    const ushort_t* h = hs + (size_t)row * H_;
    float s[C_];
#pragma unroll
    for (int c = 0; c < C_; ++c) s[c] = 0.f;
    for (int k = lane; k < H_; k += 64) {
        const float hv = bf2f(h[k]);
        const float* w = Wout + k * C_;
#pragma unroll
        for (int c = 0; c < C_; ++c) s[c] += hv * w[c];
    }
#pragma unroll
    for (int c = 0; c < C_; ++c) {
#pragma unroll
        for (int d = 32; d > 0; d >>= 1) s[c] += __shfl_xor(s[c], d);
        s[c] += bout[c];
    }
    float mx = s[0];
#pragma unroll
    for (int c = 1; c < C_; ++c) mx = fmaxf(mx, s[c]);
    float sum = 0.f;
#pragma unroll
    for (int c = 0; c < C_; ++c) { s[c] = expf(s[c] - mx); sum += s[c]; }
    const float inv = 1.0f / sum;
    if (lane < C_) {
        float pv = 0.f;
#pragma unroll
        for (int c = 0; c < C_; ++c)
            if (lane == c) pv = s[c] * inv;
        out[(size_t)row * C_ + lane] = pv;
    }
}

// ---------------------------------------------------------------------------
extern "C" void kernel_launch(void* const* d_in, const int* in_sizes, int n_in,
                              void* d_out, int out_size, void* d_ws, size_t ws_size,
                              hipStream_t stream) {
    const float* X    = (const float*)d_in[0];
    const float* W0   = (const float*)d_in[1];
    const float* b0   = (const float*)d_in[2];
    const float* W1   = (const float*)d_in[3];
    const float* b1   = (const float*)d_in[4];
    const float* Wout = (const float*)d_in[5];
    const float* bout = (const float*)d_in[6];
    float* out = (float*)d_out;

    // ws layout (~153 MiB total)
    char* p = (char*)d_ws;
    size_t off = 0;
    auto take = [&](size_t bytes) { char* r = p + off; off += bytes; return r; };
    ushort_t* W0xT_hi = (ushort_t*)take((size_t)G4_ * NA_ * 2);
    ushort_t* W0xT_lo = (ushort_t*)take((size_t)G4_ * NA_ * 2);
    ushort_t* W0hT_hi = (ushort_t*)take((size_t)G4_ * H_ * 2);
    ushort_t* W0hT_lo = (ushort_t*)take((size_t)G4_ * H_ * 2);
    ushort_t* W1T_hi  = (ushort_t*)take((size_t)G4_ * 2 * H_ * 2);
    ushort_t* W1T_lo  = (ushort_t*)take((size_t)G4_ * 2 * H_ * 2);
    ushort_t* Xc_hi   = (ushort_t*)take((size_t)MC_ * NA_ * 2);
    ushort_t* Xc_lo   = (ushort_t*)take((size_t)MC_ * NA_ * 2);
    float*    Z0c     = (float*)take((size_t)MC_ * G4_ * 4);
    ushort_t* hsb     = (ushort_t*)take((size_t)BT_ * H_ * 2);
    float*    c0      = (float*)take((size_t)B_ * H_ * 4);
    float*    c1      = (float*)take((size_t)B_ * H_ * 4);
    ushort_t* h0hi    = (ushort_t*)take((size_t)2 * HB_ * 2);
    ushort_t* h0lo    = (ushort_t*)take((size_t)2 * HB_ * 2);
    ushort_t* h1hi    = (ushort_t*)take((size_t)2 * HB_ * 2);
    ushort_t* h1lo    = (ushort_t*)take((size_t)2 * HB_ * 2);

    // Diagnostic guard: if workspace is too small, do nothing (no-crash no-op;
    // validation will fail with the "all zeros" signature instead of a GPU fault).
    if (ws_size < off) return;

    // zero-state init (parity-1 buffers are the t=-1 reads)
    hipMemsetAsync(c0, 0, (size_t)B_ * H_ * 4, stream);
    hipMemsetAsync(c1, 0, (size_t)B_ * H_ * 4, stream);
    hipMemsetAsync(h0hi + HB_, 0, (size_t)HB_ * 2, stream);
    hipMemsetAsync(h0lo + HB_, 0, (size_t)HB_ * 2, stream);
    hipMemsetAsync(h1hi + HB_, 0, (size_t)HB_ * 2, stream);
    hipMemsetAsync(h1lo + HB_, 0, (size_t)HB_ * 2, stream);

    // weight prep: decompose + transpose
    transdec<<<dim3(NA_ / 32, G4_ / 32), 256, 0, stream>>>(W0, 0,   NA_,     W0xT_hi, W0xT_lo);
    transdec<<<dim3(H_  / 32, G4_ / 32), 256, 0, stream>>>(W0, NA_, H_,      W0hT_hi, W0hT_lo);
    transdec<<<dim3(2 * H_ / 32, G4_ / 32), 256, 0, stream>>>(W1, 0, 2 * H_, W1T_hi,  W1T_lo);

    // chunked input projection + pipelined recurrent steps
    for (int c = 0; c < T_ / CH_; ++c) {
        decomp_chunk<<<(MC_ * NA_ / 4 + 255) / 256, 256, 0, stream>>>(X, c, Xc_hi, Xc_lo);
        gemm_bf16x3<<<dim3(G4_ / 128, MC_ / 128), 256, 0, stream>>>(
            Xc_hi, Xc_lo, W0xT_hi, W0xT_lo, Z0c, MC_, G4_, NA_);
        for (int j = 0; j < CH_; ++j) {
            const int t = c * CH_ + j;
            lstm_step<<<128, 512, 0, stream>>>(t, Z0c, W0hT_hi, W0hT_lo, W1T_hi, W1T_lo,
                                               b0, b1, h0hi, h0lo, h1hi, h1lo, c0, c1, hsb);
        }
    }
    // drain: final L1 step (t=128 -> L1(127))
    lstm_step<<<128, 512, 0, stream>>>(T_, Z0c, W0hT_hi, W0hT_lo, W1T_hi, W1T_lo,
                                       b0, b1, h0hi, h0lo, h1hi, h1lo, c0, c1, hsb);

    // output head
    out_softmax<<<BT_ / 4, 256, 0, stream>>>(hsb, Wout, bout, out);
}